// Round 1
// 361.948 us; speedup vs baseline: 1.0601x; 1.0601x over previous
//
#include <hip/hip_runtime.h>
#include <math.h>

// ReDrafterHead: B=64, H=4096, D=512, G3=1536, V=32000, STEPS=4
// Round 5: ALL weights pre-split once into swizzled bf16 hi/lo planes
// (tiled [N/128][K/64][128 rows][8 chunks XOR row&7][8]); GEMM B-staging is
// now a global_load_lds identity copy (no fp32 round-trip / split VALU);
// double-buffered LDS with 2-phase stage(t+1) || MFMA(t) pipeline; gates
// K-split=4 (96 blocks), in_proj K-split=16 (64 blocks).
// ws = 256 MiB (evidenced by harness 262144 KB fills); we use ~96 MiB.

typedef __attribute__((ext_vector_type(8))) short short8;   // 8 bf16
typedef __attribute__((ext_vector_type(4))) float f32x4;

__device__ __forceinline__ unsigned short f2bf_rne(float x) {
    unsigned u = __float_as_uint(x);
    unsigned r = (u + 0x7fffu + ((u >> 16) & 1u)) >> 16;
    return (unsigned short)r;
}
// hi = truncate; lo = RNE of residual. 3-pass MFMA error ~2^-16 rel.
__device__ __forceinline__ void split2(float x, unsigned short& hi, unsigned short& lo) {
    unsigned u = __float_as_uint(x);
    hi = (unsigned short)(u >> 16);
    float r = x - __uint_as_float(u & 0xffff0000u);
    lo = f2bf_rne(r);
}

// store one element into swizzled bf16 hi/lo planes, row stride 512 elems.
// layout: elem d -> kstep s=d>>6 (128B), chunk cl=(d>>3)&7 XOR (m&7), byte (d&7)*2
__device__ __forceinline__ void store_plane(unsigned short* hiP, unsigned short* loP,
                                            int m, int d, float v) {
    int s = d >> 6, cl = (d >> 3) & 7, e = d & 7;
    int off = m * 512 + s * 64 + ((cl ^ (m & 7)) * 8) + e;
    unsigned short hi, lo; split2(v, hi, lo);
    hiP[off] = hi; loP[off] = lo;
}

__device__ __forceinline__ void gload16(const void* g, void* lds) {
    __builtin_amdgcn_global_load_lds(
        (const __attribute__((address_space(1))) unsigned int*)g,
        (__attribute__((address_space(3))) unsigned int*)lds, 16, 0, 0);
}

// ---------------------------------------------------------------------------
// Weight pre-split: W[N][K] fp32 -> swizzled bf16 planes, tile-major:
// ushort off = ((nt*(K/64) + ks)*128 + row)*64 + ((c8&7)^(row&7))*8
// One thread per 8 elems; reads/writes fully coalesced at 128B granularity.
// ---------------------------------------------------------------------------
__device__ __forceinline__ void split_w_body(
    const float* __restrict__ W, unsigned short* __restrict__ H,
    unsigned short* __restrict__ L, size_t g, int kclog)
{
    int n  = (int)(g >> kclog);
    int c8 = (int)g & ((1 << kclog) - 1);
    const float* src = W + g * 8;
    float4 v0 = *(const float4*)src;
    float4 v1 = *(const float4*)(src + 4);
    unsigned short h[8], l[8];
    split2(v0.x,h[0],l[0]); split2(v0.y,h[1],l[1]); split2(v0.z,h[2],l[2]); split2(v0.w,h[3],l[3]);
    split2(v1.x,h[4],l[4]); split2(v1.y,h[5],l[5]); split2(v1.z,h[6],l[6]); split2(v1.w,h[7],l[7]);
    uint4 ph = make_uint4((unsigned)h[0]|((unsigned)h[1]<<16), (unsigned)h[2]|((unsigned)h[3]<<16),
                          (unsigned)h[4]|((unsigned)h[5]<<16), (unsigned)h[6]|((unsigned)h[7]<<16));
    uint4 pl = make_uint4((unsigned)l[0]|((unsigned)l[1]<<16), (unsigned)l[2]|((unsigned)l[3]<<16),
                          (unsigned)l[4]|((unsigned)l[5]<<16), (unsigned)l[6]|((unsigned)l[7]<<16));
    int nt = n >> 7, row = n & 127;
    int ksi = c8 >> 3;
    int slot = (c8 & 7) ^ (row & 7);
    int tpr = 1 << (kclog - 3);                 // tiles per row-tile = K/64
    size_t off = ((size_t)(nt * tpr + ksi) * 128 + row) * 64 + slot * 8;
    *(uint4*)(H + off) = ph;
    *(uint4*)(L + off) = pl;
}

__global__ __launch_bounds__(256) void k_split_W(
    const float* __restrict__ W, unsigned short* __restrict__ H,
    unsigned short* __restrict__ L, int kclog)
{
    size_t g = (size_t)blockIdx.x * 256 + threadIdx.x;
    split_w_body(W, H, L, g, kclog);
}

// 4 GRU weight matrices in one launch: grid (384, 4), blockIdx.y picks mat.
__global__ __launch_bounds__(256) void k_split_gw(
    const float* __restrict__ w0, const float* __restrict__ w1,
    const float* __restrict__ w2, const float* __restrict__ w3,
    unsigned short* __restrict__ H, unsigned short* __restrict__ L)
{
    int mat = blockIdx.y;
    const float* W = mat == 0 ? w0 : mat == 1 ? w1 : mat == 2 ? w2 : w3;
    size_t g = (size_t)blockIdx.x * 256 + threadIdx.x;     // < 98304
    split_w_body(W, H + (size_t)mat * 786432, L + (size_t)mat * 786432, g, 6);
}

// ---------------------------------------------------------------------------
// MFMA GEMM, 512 threads (8 waves). C[0..63][n0..n0+127] over nk k-steps.
// A: pre-split swizzled bf16 planes (row stride AstrideB bytes, per-row addr).
// B: pre-split swizzled tiled planes, identity global_load_lds copy.
// 2-phase double-buffered pipeline: stage(t+1) issued before MFMA(t); the
// compiler's vmcnt(0)-before-s_barrier drains the remainder (guide §5 T3 min).
// ---------------------------------------------------------------------------
template<bool ARGMAX>
__device__ __forceinline__ void mfma_gemm(
    const char* __restrict__ AH, const char* __restrict__ AL, int AstrideB, int akk0,
    const unsigned short* __restrict__ BH, const unsigned short* __restrict__ BL,
    size_t btileU,            // ushort offset of first k-step tile (8192 ushorts each)
    int nk,
    float* __restrict__ C, int ldc, int n0,
    unsigned short (*AsH)[4096], unsigned short (*AsL)[4096],
    unsigned short (*BsH)[8192], unsigned short (*BsL)[8192],
    float* __restrict__ pval, int* __restrict__ pidx, int bx)
{
    const int tid  = threadIdx.x;
    const int wv   = tid >> 6;
    const int lane = tid & 63;
    const int lr   = lane & 15;
    const int lh   = lane >> 4;
    const int m    = tid >> 3;       // A staging: row 0..63
    const int cp   = tid & 7;        // A staging: chunk 0..7

    f32x4 acc[4];
#pragma unroll
    for (int i = 0; i < 4; ++i) acc[i] = (f32x4){0.f, 0.f, 0.f, 0.f};

    auto stage = [&](int t, int p) {
        // A tiles: identity copy of swizzled planes (wave wv -> rows wv*8..+7)
        const int ka = (akk0 + t * 64) * 2;
        gload16(AH + m * AstrideB + ka + cp * 16, (char*)AsH[p] + wv * 1024);
        gload16(AL + m * AstrideB + ka + cp * 16, (char*)AsL[p] + wv * 1024);
        // B tile: LDS layout == global tile layout -> pure linear copy
        const char* bH = (const char*)BH + (btileU + (size_t)t * 8192) * 2;
        const char* bL = (const char*)BL + (btileU + (size_t)t * 8192) * 2;
        gload16(bH + wv * 2048 +        lane * 16, (char*)BsH[p] + wv * 2048);
        gload16(bH + wv * 2048 + 1024 + lane * 16, (char*)BsH[p] + wv * 2048 + 1024);
        gload16(bL + wv * 2048 +        lane * 16, (char*)BsL[p] + wv * 2048);
        gload16(bL + wv * 2048 + 1024 + lane * 16, (char*)BsL[p] + wv * 2048 + 1024);
    };

    stage(0, 0);
    __syncthreads();                 // compiler emits vmcnt(0) before s_barrier

    for (int t = 0; t < nk; ++t) {
        const int p = t & 1;
        if (t + 1 < nk) stage(t + 1, p ^ 1);   // prefetch: latency hides under MFMA
#pragma unroll
        for (int kk2 = 0; kk2 < 2; ++kk2) {
            int aoff = lr * 64 + (((kk2 * 4 + lh) ^ (lr & 7)) * 8);
            short8 ah[4], al[4];
#pragma unroll
            for (int mt = 0; mt < 4; ++mt) {
                ah[mt] = *(const short8*)(AsH[p] + mt * 1024 + aoff);
                al[mt] = *(const short8*)(AsL[p] + mt * 1024 + aoff);
            }
            int brow = wv * 16 + lr;
            int boff = brow * 64 + (((kk2 * 4 + lh) ^ (brow & 7)) * 8);
            short8 bh = *(const short8*)(BsH[p] + boff);
            short8 bl = *(const short8*)(BsL[p] + boff);
#pragma unroll
            for (int mt = 0; mt < 4; ++mt) {
                acc[mt] = __builtin_amdgcn_mfma_f32_16x16x32_bf16(ah[mt], bh, acc[mt], 0, 0, 0);
                acc[mt] = __builtin_amdgcn_mfma_f32_16x16x32_bf16(ah[mt], bl, acc[mt], 0, 0, 0);
                acc[mt] = __builtin_amdgcn_mfma_f32_16x16x32_bf16(al[mt], bh, acc[mt], 0, 0, 0);
            }
        }
        __syncthreads();             // also drains the just-issued prefetch (iter-end)
    }

    // ---- epilogue: D mapping col=lane&15, row=(lane>>4)*4+i ----
#pragma unroll
    for (int mt = 0; mt < 4; ++mt)
#pragma unroll
        for (int i = 0; i < 4; ++i) {
            int mm = mt * 16 + lh * 4 + i;
            C[mm * ldc + n0 + wv * 16 + lr] = acc[mt][i];
        }

    if (ARGMAX) {
        float* sv = (float*)&AsH[0][0];   // scratch: 8*64 floats
        int*   sc = (int*)&AsL[0][0];
#pragma unroll
        for (int mt = 0; mt < 4; ++mt)
#pragma unroll
            for (int i = 0; i < 4; ++i) {
                float v = acc[mt][i];
                int   c = n0 + wv * 16 + lr;
#pragma unroll
                for (int msk = 1; msk < 16; msk <<= 1) {
                    float ov = __shfl_xor(v, msk, 64);
                    int   oc = __shfl_xor(c, msk, 64);
                    if (ov > v || (ov == v && oc < c)) { v = ov; c = oc; }
                }
                if (lr == 0) {
                    int row = mt * 16 + lh * 4 + i;
                    sv[wv * 64 + row] = v;
                    sc[wv * 64 + row] = c;
                }
            }
        __syncthreads();
        if (tid < 64) {
            float v = sv[tid]; int c = sc[tid];
#pragma unroll
            for (int w = 1; w < 8; ++w) {
                float ov = sv[w * 64 + tid]; int oc = sc[w * 64 + tid];
                if (ov > v) { v = ov; c = oc; }   // ascending col order -> first-occurrence
            }
            pval[bx * 64 + tid] = v;
            pidx[bx * 64 + tid] = c;
        }
    }
}

#define DECLARE_LDS() \
    __shared__ alignas(16) unsigned short AsH[2][4096]; \
    __shared__ alignas(16) unsigned short AsL[2][4096]; \
    __shared__ alignas(16) unsigned short BsH[2][8192]; \
    __shared__ alignas(16) unsigned short BsL[2][8192];   /* 96 KiB total */

// ---------------------------------------------------------------------------
// split hidden[64,4096] fp32 -> swizzled bf16 planes (row stride 8192 B)
// ---------------------------------------------------------------------------
__global__ __launch_bounds__(256) void k_split_A(
    const float* __restrict__ hidden, char* __restrict__ hidH, char* __restrict__ hidL)
{
    int g = blockIdx.x * 256 + threadIdx.x;   // 32768 chunks
    int m = g >> 9;
    int cc = g & 511;
    int s = cc >> 3, cl = cc & 7;
    const float* src = hidden + m * 4096 + cc * 8;
    float4 v0 = *(const float4*)src;
    float4 v1 = *(const float4*)(src + 4);
    unsigned short h[8], l[8];
    split2(v0.x,h[0],l[0]); split2(v0.y,h[1],l[1]); split2(v0.z,h[2],l[2]); split2(v0.w,h[3],l[3]);
    split2(v1.x,h[4],l[4]); split2(v1.y,h[5],l[5]); split2(v1.z,h[6],l[6]); split2(v1.w,h[7],l[7]);
    uint4 ph = make_uint4((unsigned)h[0]|((unsigned)h[1]<<16), (unsigned)h[2]|((unsigned)h[3]<<16),
                          (unsigned)h[4]|((unsigned)h[5]<<16), (unsigned)h[6]|((unsigned)h[7]<<16));
    uint4 pl = make_uint4((unsigned)l[0]|((unsigned)l[1]<<16), (unsigned)l[2]|((unsigned)l[3]<<16),
                          (unsigned)l[4]|((unsigned)l[5]<<16), (unsigned)l[6]|((unsigned)l[7]<<16));
    int off = m * 8192 + s * 128 + ((cl ^ (m & 7)) * 16);
    *(uint4*)(hidH + off) = ph;
    *(uint4*)(hidL + off) = pl;
}

// ---------------------------------------------------------------------------
// in_proj: part[ks][64][512] = hidden @ in_w^T, 64 blocks (4 nt x 16 ks)
// ---------------------------------------------------------------------------
__global__ __launch_bounds__(512) void k_inproj(
    const char* __restrict__ hidH, const char* __restrict__ hidL,
    const unsigned short* __restrict__ WH, const unsigned short* __restrict__ WL,
    float* __restrict__ part)
{
    DECLARE_LDS();
    int nt = blockIdx.x & 3;
    int ks = blockIdx.x >> 2;                 // 0..15, klen=256 (4 k-steps)
    mfma_gemm<false>(hidH, hidL, 8192, ks * 256,
                     WH, WL, (size_t)(nt * 64 + ks * 4) * 8192, 4,
                     part + ks * 32768, 512, nt * 128,
                     AsH, AsL, BsH, BsL, nullptr, nullptr, 0);
}

__global__ __launch_bounds__(256) void k_reduce_inproj(
    const float* __restrict__ part, const float* __restrict__ bias,
    float* __restrict__ hA, float* __restrict__ hB,
    unsigned short* hAH, unsigned short* hAL,
    unsigned short* hBH, unsigned short* hBL,
    unsigned short* xH,  unsigned short* xL)
{
    int i = blockIdx.x * 256 + threadIdx.x;   // < 32768
    int b = i >> 9;
    int d = i & 511;
    float s = bias[d];
#pragma unroll
    for (int ks = 0; ks < 16; ++ks) s += part[ks * 32768 + i];
    hA[i] = s;
    hB[i] = s;
    store_plane(hAH, hAL, b, d, s);
    store_plane(hBH, hBL, b, d, s);
    store_plane(xH,  xL,  b, d, 0.f);
}

// ---------------------------------------------------------------------------
// GRU gates, K-split 4: 96 blocks (12 nt x 4 ks x 2 mat), klen=128 (2 k-steps)
// gw planes packed [w_ih0, w_hh0, w_ih1, w_hh1], 96 tiles each.
// ---------------------------------------------------------------------------
__global__ __launch_bounds__(512) void k_gates(
    const char* __restrict__ xH, const char* __restrict__ xL,
    const char* __restrict__ hH, const char* __restrict__ hL,
    const unsigned short* __restrict__ gwH, const unsigned short* __restrict__ gwL,
    int layer, float* __restrict__ gip, float* __restrict__ ghp)
{
    DECLARE_LDS();
    int bx  = blockIdx.x;
    int nt  = bx % 12;
    int ks  = (bx / 12) & 3;
    int mat = bx / 48;
    const char* AH = mat ? hH : xH;
    const char* AL = mat ? hL : xL;
    float* C = (mat ? ghp : gip) + ks * 98304;
    size_t btile = ((size_t)(layer * 2 + mat) * 96 + nt * 8 + ks * 2) * 8192;
    mfma_gemm<false>(AH, AL, 1024, ks * 128,
                     gwH, gwL, btile, 2,
                     C, 1536, nt * 128,
                     AsH, AsL, BsH, BsL, nullptr, nullptr, 0);
}

__global__ __launch_bounds__(256) void k_combine(
    const float* __restrict__ gip, const float* __restrict__ ghp,
    const float* __restrict__ b_ih, const float* __restrict__ b_hh,
    float* __restrict__ h, unsigned short* hH, unsigned short* hL)
{
    int i = blockIdx.x * 256 + threadIdx.x;   // < 32768
    int b = i >> 9;
    int d = i & 511;
    int base = b * 1536 + d;
    float ir = b_ih[d], iz = b_ih[d + 512], inn = b_ih[d + 1024];
    float hr = b_hh[d], hz = b_hh[d + 512], hn = b_hh[d + 1024];
#pragma unroll
    for (int ks = 0; ks < 4; ++ks) {
        const float* gi = gip + ks * 98304 + base;
        const float* gh = ghp + ks * 98304 + base;
        ir  += gi[0];    iz += gi[512];  inn += gi[1024];
        hr  += gh[0];    hz += gh[512];  hn  += gh[1024];
    }
    float r = 1.f / (1.f + expf(-(ir + hr)));
    float z = 1.f / (1.f + expf(-(iz + hz)));
    float n = tanhf(inn + r * hn);
    float hv = (1.f - z) * n + z * h[i];
    h[i] = hv;
    store_plane(hH, hL, b, d, hv);
}

// ---------------------------------------------------------------------------
// logits + fused per-block argmax partials. grid = 250.
// ---------------------------------------------------------------------------
__global__ __launch_bounds__(512) void k_logits(
    const char* __restrict__ hH, const char* __restrict__ hL,
    const unsigned short* __restrict__ WH, const unsigned short* __restrict__ WL,
    float* __restrict__ out, int step,
    float* __restrict__ pval, int* __restrict__ pidx)
{
    DECLARE_LDS();
    mfma_gemm<true>(hH, hL, 1024, 0,
                    WH, WL, (size_t)blockIdx.x * 8 * 8192, 8,
                    out + step * 32000, 128000, blockIdx.x * 128,
                    AsH, AsL, BsH, BsL, pval, pidx, blockIdx.x);
}

// ---------------------------------------------------------------------------
// reduce 250 argmax partials (np first-occurrence) + embed gather -> x planes
// ---------------------------------------------------------------------------
__global__ __launch_bounds__(256) void k_reduce_embed(
    const float* __restrict__ pval, const int* __restrict__ pidx,
    const float* __restrict__ embed, unsigned short* xH, unsigned short* xL)
{
    __shared__ float sv[256];
    __shared__ int   sc[256];
    const int b = blockIdx.x;
    const int tid = threadIdx.x;
    float v = -3.4e38f;
    int   c = 0x7fffffff;
    if (tid < 250) { v = pval[tid * 64 + b]; c = pidx[tid * 64 + b]; }
    sv[tid] = v; sc[tid] = c;
    __syncthreads();
    for (int s = 128; s > 0; s >>= 1) {
        if (tid < s) {
            float ov = sv[tid + s]; int oc = sc[tid + s];
            if (ov > sv[tid] || (ov == sv[tid] && oc < sc[tid])) { sv[tid] = ov; sc[tid] = oc; }
        }
        __syncthreads();
    }
    int tok = sc[0];
    for (int j = tid; j < 512; j += 256)
        store_plane(xH, xL, b, j, embed[tok * 512 + j]);
}

// ---------------------------------------------------------------------------
extern "C" void kernel_launch(void* const* d_in, const int* in_sizes, int n_in,
                              void* d_out, int out_size, void* d_ws, size_t ws_size,
                              hipStream_t stream)
{
    const float* hidden = (const float*)d_in[0];
    const float* in_w   = (const float*)d_in[1];
    const float* in_b   = (const float*)d_in[2];
    const float* w_ih0  = (const float*)d_in[3];
    const float* w_hh0  = (const float*)d_in[4];
    const float* b_ih0  = (const float*)d_in[5];
    const float* b_hh0  = (const float*)d_in[6];
    const float* w_ih1  = (const float*)d_in[7];
    const float* w_hh1  = (const float*)d_in[8];
    const float* b_ih1  = (const float*)d_in[9];
    const float* b_hh1  = (const float*)d_in[10];
    const float* embed  = (const float*)d_in[11];
    const float* out_w  = (const float*)d_in[12];
    float* out = (float*)d_out;                    // [64, 4, 32000]
    char*  ws  = (char*)d_ws;

    // ws layout (bytes) — total ~96 MiB of the 256 MiB workspace
    float* hA  = (float*)(ws + 0);                 // 131072
    float* hB  = (float*)(ws + 131072);            // 131072
    unsigned short* xH  = (unsigned short*)(ws + 262144);   // 65536 each
    unsigned short* xL  = (unsigned short*)(ws + 327680);
    unsigned short* hAH = (unsigned short*)(ws + 393216);
    unsigned short* hAL = (unsigned short*)(ws + 458752);
    unsigned short* hBH = (unsigned short*)(ws + 524288);
    unsigned short* hBL = (unsigned short*)(ws + 589824);
    char* hidH = ws + 655360;                      // 524288
    char* hidL = ws + 1179648;                     // 524288
    float* gip = (float*)(ws + 1703936);           // 4*98304 fl = 1572864 B
    float* ghp = (float*)(ws + 3276800);           // 1572864 B
    float* pval = (float*)(ws + 4849664);          // 64000
    int*   pidx = (int*)  (ws + 4913664);          // 64000
    float* ipart = (float*)(ws + 4980736);         // 16*32768 fl = 2097152 B
    unsigned short* owH = (unsigned short*)(ws + 8388608);    // 32768000
    unsigned short* owL = (unsigned short*)(ws + 41943040);   // 32768000
    unsigned short* gwH = (unsigned short*)(ws + 75497472);   // 6291456
    unsigned short* gwL = (unsigned short*)(ws + 83886080);   // 6291456
    unsigned short* inH = (unsigned short*)(ws + 92274688);   // 4194304
    unsigned short* inL = (unsigned short*)(ws + 96468992);   // 4194304 -> end 96 MiB

    // ---- prologue: split activations + ALL weights into bf16 hi/lo planes
    k_split_A<<<128, 256, 0, stream>>>(hidden, hidH, hidL);
    k_split_W<<<8000, 256, 0, stream>>>(out_w, owH, owL, 6);           // 32000x512
    k_split_gw<<<dim3(384, 4), 256, 0, stream>>>(w_ih0, w_hh0, w_ih1, w_hh1, gwH, gwL);
    k_split_W<<<1024, 256, 0, stream>>>(in_w, inH, inL, 9);            // 512x4096
    k_inproj<<<64, 512, 0, stream>>>(hidH, hidL, inH, inL, ipart);
    k_reduce_inproj<<<128, 256, 0, stream>>>(ipart, in_b, hA, hB,
                                             hAH, hAL, hBH, hBL, xH, xL);

    for (int step = 0; step < 4; ++step) {
        k_gates<<<96, 512, 0, stream>>>((char*)xH, (char*)xL, (char*)hAH, (char*)hAL,
                                        gwH, gwL, 0, gip, ghp);
        k_combine<<<128, 256, 0, stream>>>(gip, ghp, b_ih0, b_hh0, hA, hAH, hAL);
        k_gates<<<96, 512, 0, stream>>>((char*)hAH, (char*)hAL, (char*)hBH, (char*)hBL,
                                        gwH, gwL, 1, gip, ghp);
        k_combine<<<128, 256, 0, stream>>>(gip, ghp, b_ih1, b_hh1, hB, hBH, hBL);
        k_logits<<<250, 512, 0, stream>>>((char*)hBH, (char*)hBL, owH, owL,
                                          out, step, pval, pidx);
        k_reduce_embed<<<64, 256, 0, stream>>>(pval, pidx, embed, xH, xL);
    }
}